// Round 4
// baseline (655.203 us; speedup 1.0000x reference)
//
#include <hip/hip_runtime.h>
#include <stdint.h>

// Problem constants (fixed by reference setup_inputs)
#define BB 32
#define NN 131072            // 2^17 points per batch
#define BN (BB * NN)         // 4,194,304 = 2^22
#define TT 32768             // NUM_POINTS_TARGET
#define CELL 0.05f
#define TBITS 18
#define TSIZE (1 << TBITS)   // 262,144 slots per batch table (1 MB at 4B/slot)
#define TMASK (TSIZE - 1)
#define EMPTY32 0xFFFFFFFFu
#define LI17 0x1FFFFu        // low 17 bits = local point index

// Output layout in d_out (floats), in return order:
// y_sel [32,32768,3], idx_out [32,32768,2], mask_sel [32,32768],
// ul_idx [BN], ul_idx_inv [BN]
#define Y_OFF   0
#define IDX_OFF (BB * TT * 3)                    // 3,145,728
#define MSK_OFF (IDX_OFF + BB * TT * 2)          // 5,242,880
#define ULI_OFF (MSK_OFF + BB * TT)              // 6,291,456
#define ULV_OFF (ULI_OFF + BN)                   // 10,485,760

#define SCAN_TPB 256
#define SCAN_EPT 16
#define SCAN_EPB (SCAN_TPB * SCAN_EPT)           // 4096
#define SCAN_NBLK (BN / SCAN_EPB)                // 1024 (32 per batch)

typedef float v4f __attribute__((ext_vector_type(4)));
typedef int   v4i __attribute__((ext_vector_type(4)));
typedef unsigned int v4u __attribute__((ext_vector_type(4)));

// Quantize x -> 30-bit packed voxel key. 4 points/thread, float4 loads.
// y is reconstructible exactly: CELL*(float)g == CELL*rintf(x/CELL).
__global__ void k_keygen(const float* __restrict__ x, unsigned int* __restrict__ keys) {
    int t = blockIdx.x * blockDim.x + threadIdx.x;   // handles points 4t..4t+3
    const v4f* xv = (const v4f*)(x + 12 * t);        // 48B per thread, 16B aligned
    v4f va = __builtin_nontemporal_load(xv + 0);
    v4f vb = __builtin_nontemporal_load(xv + 1);
    v4f vc = __builtin_nontemporal_load(xv + 2);
    float p[12];
    p[0] = va[0]; p[1] = va[1]; p[2]  = va[2]; p[3]  = va[3];
    p[4] = vb[0]; p[5] = vb[1]; p[6]  = vb[2]; p[7]  = vb[3];
    p[8] = vc[0]; p[9] = vc[1]; p[10] = vc[2]; p[11] = vc[3];
    v4u kv;
    #pragma unroll
    for (int q = 0; q < 4; q++) {
        int g0 = (int)rintf(p[3 * q + 0] / CELL) + 512;
        int g1 = (int)rintf(p[3 * q + 1] / CELL) + 512;
        int g2 = (int)rintf(p[3 * q + 2] / CELL) + 512;
        g0 = min(max(g0, 0), 1023); g1 = min(max(g1, 0), 1023); g2 = min(max(g2, 0), 1023);
        kv[q] = ((unsigned int)g0 << 20) | ((unsigned int)g1 << 10) | (unsigned int)g2;
    }
    __builtin_nontemporal_store(kv, (v4u*)keys + t);
}

// Per-batch hash insert, ROUND 4: ONE workgroup per batch (32 x 1024 threads,
// 128 pts/thread). The WG is the sole writer of its 1 MB table, so
// WORKGROUP-scope atomics are architecturally sufficient (no cross-WG
// coherence needed) and execute in the local XCD L2 instead of crossing the
// L2->fabric boundary per op (rounds 0-3 showed device-scope atomics cost one
// ~64B fabric write-through each at ~25 G ops/s — the whole bottleneck).
// The WG also clears its own table in-kernel (kills the 32 MB memset dispatch
// and the clean-line refetch on first touch). Kernel-end release flushes L2,
// so downstream kernels' plain reads of tab are correct.
// Entries monotonically decrease => raced reads remain safe.
__global__ __launch_bounds__(1024, 1) void k_insert(
        const unsigned int* __restrict__ keys,
        unsigned int* __restrict__ tab_all,
        int* __restrict__ slotArr) {
    int b = blockIdx.x;                    // 32 blocks = 32 batches
    int t = threadIdx.x;                   // 1024 threads
    unsigned int* tab = tab_all + ((size_t)b << TBITS);

    // Clear this batch's table: 64 iters x 1024 threads x 16B = 1 MB, coalesced.
    v4u ff; ff[0] = EMPTY32; ff[1] = EMPTY32; ff[2] = EMPTY32; ff[3] = EMPTY32;
    v4u* tv = (v4u*)tab;
    #pragma unroll
    for (int q = 0; q < 64; q++) tv[(q << 10) | t] = ff;
    __syncthreads();

    const unsigned int* bkeys = keys + (b << 17);
    int* bslot = slotArr + (b << 17);
    unsigned int key_next = bkeys[t];      // prefetch iter 0
    for (int e = 0; e < 128; e++) {
        unsigned int key = key_next;
        int li = (e << 10) | t;            // stride-1024: coalesced loads/stores
        if (e < 127) key_next = bkeys[li + 1024];   // hide next key load under CAS
        unsigned int s = (key * 2654435761u) >> (32 - TBITS);
        unsigned int tag = (key * 0x85EBCA6Bu) >> 26;        // independent 6-bit tag
        unsigned int mine = (tag << 17) | (unsigned int)li;  // < 2^23 < EMPTY32
        for (;;) {
            unsigned int expected = EMPTY32;
            if (__hip_atomic_compare_exchange_strong(&tab[s], &expected, mine,
                    __ATOMIC_RELAXED, __ATOMIC_RELAXED, __HIP_MEMORY_SCOPE_WORKGROUP))
                break;                                   // claimed fresh slot
            unsigned int old = expected;
            if ((old >> 17) == tag && bkeys[old & LI17] == key) {  // same voxel
                if (mine < old)                          // rare (converges fast)
                    __hip_atomic_fetch_min(&tab[s], mine, __ATOMIC_RELAXED,
                                           __HIP_MEMORY_SCOPE_WORKGROUP);
                break;
            }
            s = (s + 1) & TMASK;                         // different key: probe on
        }
        bslot[li] = (int)s;
    }
}

// Scan pass A: resolve first-occurrence position per point from the table;
// flag bitmask; block partial sums. Same %32 XCD swizzle.
// Streams (slotArr read, pfirst write) vectorized to int4.
__global__ void k_scanA(const int* __restrict__ slotArr,
                        const unsigned int* __restrict__ tab_all,
                        int* __restrict__ pfirst, unsigned short* __restrict__ fmask,
                        int* __restrict__ bsums) {
    int blk = blockIdx.x;
    int b = blk & 31;
    int chunk = blk >> 5;                  // < 32
    int fbid = (b << 5) + chunk;           // flat-order block id for bsums/fmask
    int t = threadIdx.x;
    int base = (b << 17) + chunk * SCAN_EPB + t * SCAN_EPT;  // flat, mult of 16
    const unsigned int* tab = tab_all + ((size_t)b << TBITS);
    int bbase = b << 17;
    int s = 0;
    unsigned int bits = 0;
    const v4i* slv = (const v4i*)(slotArr + base);
    v4i* pfv = (v4i*)(pfirst + base);
    #pragma unroll
    for (int q = 0; q < 4; q++) {
        v4i sl = slv[q];
        v4i pv;
        #pragma unroll
        for (int e = 0; e < 4; e++) {
            int idx = 4 * q + e;
            int p = (int)(tab[sl[e]] & LI17) + bbase;
            pv[e] = p;
            int f = (p == base + idx);
            bits |= (unsigned int)f << idx;
            s += f;
        }
        pfv[q] = pv;
    }
    fmask[fbid * SCAN_TPB + t] = (unsigned short)bits;
    __shared__ int sh[SCAN_TPB];
    sh[t] = s;
    __syncthreads();
    for (int off = SCAN_TPB / 2; off > 0; off >>= 1) {
        if (t < off) sh[t] += sh[t + off];
        __syncthreads();
    }
    if (t == 0) bsums[fbid] = sh[0];
}

// Scan pass C with fused pass B: every block redundantly scans the 1024 RAW
// block sums (4 KB, L2-broadcast after first block) -> its own exclusive
// block prefix + grand total; removes the serializing 1-block scanB dispatch.
// Then per-element exclusive scan; scatter ul_idx_inv[rank] = pos; int4 stores.
__global__ void k_scanC(const unsigned short* __restrict__ fmask,
                        const int* __restrict__ bsums,
                        int* __restrict__ scanArr, float* __restrict__ ulinv,
                        int* __restrict__ scal) {
    int t = threadIdx.x;
    __shared__ int shc[SCAN_TPB];
    // --- fused scanB: inclusive scan of 256 chunk-sums (4 bsums per thread) ---
    int s0 = bsums[4 * t + 0], s1 = bsums[4 * t + 1];
    int s2 = bsums[4 * t + 2], s3 = bsums[4 * t + 3];
    int cs = s0 + s1 + s2 + s3;
    shc[t] = cs;
    __syncthreads();
    for (int off = 1; off < SCAN_TPB; off <<= 1) {
        int add = (t >= off) ? shc[t - off] : 0;
        __syncthreads();
        shc[t] += add;
        __syncthreads();
    }
    __shared__ int bp;
    int q = blockIdx.x >> 2, r = blockIdx.x & 3;
    if (t == q) {
        int ex = shc[t] - cs;              // exclusive prefix of chunk q
        if (r > 0) ex += s0;
        if (r > 1) ex += s1;
        if (r > 2) ex += s2;
        bp = ex;                           // sum of bsums[0 .. blockIdx.x)
    }
    if (blockIdx.x == 0 && t == SCAN_TPB - 1) scal[2] = shc[t];  // total U
    __syncthreads();
    int blockpref = bp;
    // --- per-element scan within this block ---
    unsigned int bits = fmask[blockIdx.x * SCAN_TPB + t];
    int s = __popc(bits);
    __syncthreads();                       // shc reuse
    shc[t] = s;
    __syncthreads();
    int v = s;
    for (int off = 1; off < SCAN_TPB; off <<= 1) {
        int add = (t >= off) ? shc[t - off] : 0;
        __syncthreads();
        shc[t] += add;
        __syncthreads();
    }
    int prefix = blockpref + shc[t] - v;   // exclusive prefix for this thread
    int base = blockIdx.x * SCAN_EPB + t * SCAN_EPT;   // mult of 16
    v4i* out = (v4i*)(scanArr + base);
    #pragma unroll
    for (int qq = 0; qq < 4; qq++) {
        v4i o;
        #pragma unroll
        for (int e = 0; e < 4; e++) {
            int idx = 4 * qq + e;
            int f = (bits >> idx) & 1;
            o[e] = prefix;
            if (f) ulinv[prefix] = (float)(base + idx);
            prefix += f;
        }
        out[qq] = o;
    }
}

// Fused: ul_idx gather + ul_idx_inv tail pad + stable top-k partition + output
// gather. y reconstructed exactly from the packed key (no x read). %32 swizzle
// keeps the scanArr[pfirst[i]] gather in the batch's 512 KB window.
// 4 points/thread: int4 stream loads (pfirst, scanArr, keys), vec uli store.
__global__ void k_select(const unsigned int* __restrict__ keys,
                         const int* __restrict__ pfirst,
                         const int* __restrict__ scanArr,
                         const unsigned short* __restrict__ fmask,
                         const int* __restrict__ scal,
                         float* __restrict__ ysel, float* __restrict__ idxout,
                         float* __restrict__ msel, float* __restrict__ uli,
                         float* __restrict__ ulinv) {
    int blk = blockIdx.x;                  // BN/1024 = 4096 blocks
    int b = blk & 31;
    int chunk = blk >> 5;                  // 0..127
    int j0 = (chunk << 10) + (threadIdx.x << 2);   // local idx of first point
    int i0 = (b << 17) + j0;               // flat, mult of 4 -> 16B aligned
    v4i pf = *(const v4i*)(pfirst + i0);
    v4i sa = *(const v4i*)(scanArr + i0);
    v4u kv = *(const v4u*)(keys + i0);
    int U = scal[2];
    int base = scanArr[b << 17];           // uniform per batch
    int cnt1 = ((b == BB - 1) ? U : scanArr[(b + 1) << 17]) - base;
    unsigned int fb = fmask[i0 >> 4];      // 4 consecutive i share one u16
    v4f ul;
    #pragma unroll
    for (int e = 0; e < 4; e++) ul[e] = (float)scanArr[pf[e]];
    __builtin_nontemporal_store(ul, (v4f*)(uli + i0));
    #pragma unroll
    for (int e = 0; e < 4; e++) {
        int i = i0 + e;
        int j = j0 + e;
        if (i >= U) ulinv[i] = (float)BN;  // sentinel tail
        int ones_before = sa[e] - base;
        int flag = (fb >> (i & 15)) & 1;
        int pos = flag ? ones_before : cnt1 + (j - ones_before);
        if (pos < TT) {
            unsigned int key = kv[e];
            float y0 = CELL * (float)((int)(key >> 20) - 512);
            float y1 = CELL * (float)((int)((key >> 10) & 1023) - 512);
            float y2 = CELL * (float)((int)(key & 1023) - 512);
            int yo = (b * TT + pos) * 3;
            ysel[yo + 0] = y0;
            ysel[yo + 1] = y1;
            ysel[yo + 2] = y2;
            int io = (b * TT + pos) * 2;
            idxout[io + 0] = (float)b;
            idxout[io + 1] = (float)j;
            msel[b * TT + pos] = flag ? 1.0f : 0.0f;
        }
    }
}

extern "C" void kernel_launch(void* const* d_in, const int* in_sizes, int n_in,
                              void* d_out, int out_size, void* d_ws, size_t ws_size,
                              hipStream_t stream) {
    const float* x = (const float*)d_in[0];
    float* out = (float*)d_out;
    char* ws = (char*)d_ws;

    // ws layout (bytes): scalars 256 | slotArr BN*4 | pfirst BN*4 | scanArr BN*4
    //                    | bsums 4096 | fmask BN/16*2 | keys BN*4 | tab 32*TSIZE*4
    //                    => ~97 MB
    int* scal    = (int*)ws;
    int* slotArr = (int*)(ws + 256);
    int* pfirst  = slotArr + BN;
    int* scanArr = pfirst + BN;
    int* bsums   = scanArr + BN;
    unsigned short* fmask = (unsigned short*)(bsums + 1024);
    unsigned int* keys = (unsigned int*)((char*)fmask + (BN / 16) * 2);
    unsigned int* tab  = keys + BN;

    // Table clear is fused into k_insert (each WG clears its own 1 MB in-L2).
    k_keygen<<<BN / 4 / 256, 256, 0, stream>>>(x, keys);
    k_insert<<<BB, 1024, 0, stream>>>(keys, tab, slotArr);
    k_scanA<<<SCAN_NBLK, SCAN_TPB, 0, stream>>>(slotArr, tab, pfirst, fmask, bsums);
    k_scanC<<<SCAN_NBLK, SCAN_TPB, 0, stream>>>(fmask, bsums, scanArr, out + ULV_OFF,
                                                scal);
    k_select<<<BN / 1024, 256, 0, stream>>>(keys, pfirst, scanArr, fmask, scal,
                                            out + Y_OFF, out + IDX_OFF, out + MSK_OFF,
                                            out + ULI_OFF, out + ULV_OFF);
}

// Round 5
// 262.754 us; speedup vs baseline: 2.4936x; 2.4936x over previous
//
#include <hip/hip_runtime.h>
#include <stdint.h>

// Problem constants (fixed by reference setup_inputs)
#define BB 32
#define NN 131072            // 2^17 points per batch
#define BN (BB * NN)         // 4,194,304 = 2^22
#define TT 32768             // NUM_POINTS_TARGET
#define CELL 0.05f
#define EMPTY32 0xFFFFFFFFu

// Output layout in d_out (floats), in return order:
// y_sel [32,32768,3], idx_out [32,32768,2], mask_sel [32,32768],
// ul_idx [BN], ul_idx_inv [BN]
#define Y_OFF   0
#define IDX_OFF (BB * TT * 3)                    // 3,145,728
#define MSK_OFF (IDX_OFF + BB * TT * 2)          // 5,242,880
#define ULI_OFF (MSK_OFF + BB * TT)              // 6,291,456
#define ULV_OFF (ULI_OFF + BN)                   // 10,485,760

#define SCAN_TPB 256
#define SCAN_EPT 16
#define SCAN_EPB (SCAN_TPB * SCAN_EPT)           // 4096
#define SCAN_NBLK (BN / SCAN_EPB)                // 1024

// Bucket-partition pipeline (NO global atomics — rounds 0-4 proved every
// global atomic is a memory-side RMW at ~25 G ops/s regardless of scope;
// 4M+ of them floor-bound the old k_insert at ~150 us).
#define NBK 1024             // hash buckets per batch
#define CHE 4096             // elems per chunk
#define NCH (BN / CHE)       // 1024 chunks total, 32 per batch
#define BPB 8                // buckets per dedup block
#define P4B (BB * NBK / BPB) // 4096 dedup blocks
#define HSLOTS 4096
#define HMASK (HSLOTS - 1)

typedef float v4f __attribute__((ext_vector_type(4)));
typedef int   v4i __attribute__((ext_vector_type(4)));
typedef unsigned int v4u __attribute__((ext_vector_type(4)));

__device__ __forceinline__ unsigned bucket_of(unsigned key) {
    return (key * 2654435761u) >> 22;            // top 10 bits of mult-hash
}

// Quantize x -> 30-bit packed voxel key. 4 points/thread, float4 loads.
// y is reconstructible exactly: CELL*(float)g == CELL*rintf(x/CELL).
__global__ void k_keygen(const float* __restrict__ x, unsigned int* __restrict__ keys) {
    int t = blockIdx.x * blockDim.x + threadIdx.x;   // handles points 4t..4t+3
    const v4f* xv = (const v4f*)(x + 12 * t);        // 48B per thread, 16B aligned
    v4f va = __builtin_nontemporal_load(xv + 0);
    v4f vb = __builtin_nontemporal_load(xv + 1);
    v4f vc = __builtin_nontemporal_load(xv + 2);
    float p[12];
    p[0] = va[0]; p[1] = va[1]; p[2]  = va[2]; p[3]  = va[3];
    p[4] = vb[0]; p[5] = vb[1]; p[6]  = vb[2]; p[7]  = vb[3];
    p[8] = vc[0]; p[9] = vc[1]; p[10] = vc[2]; p[11] = vc[3];
    v4u kv;
    #pragma unroll
    for (int q = 0; q < 4; q++) {
        int g0 = (int)rintf(p[3 * q + 0] / CELL) + 512;
        int g1 = (int)rintf(p[3 * q + 1] / CELL) + 512;
        int g2 = (int)rintf(p[3 * q + 2] / CELL) + 512;
        g0 = min(max(g0, 0), 1023); g1 = min(max(g1, 0), 1023); g2 = min(max(g2, 0), 1023);
        kv[q] = ((unsigned int)g0 << 20) | ((unsigned int)g1 << 10) | (unsigned int)g2;
    }
    __builtin_nontemporal_store(kv, (v4u*)keys + t);
}

// P1: per-chunk bucket histogram (LDS only).
__global__ void k_hist(const unsigned int* __restrict__ keys, int* __restrict__ hist) {
    __shared__ int h[NBK];
    int c = blockIdx.x, t = threadIdx.x;
    for (int k = t; k < NBK; k += 256) h[k] = 0;
    __syncthreads();
    int b = c >> 5, cb = c & 31;
    const unsigned int* kk = keys + (b << 17) + (cb << 12);
    for (int e = t; e < CHE; e += 256)
        atomicAdd(&h[bucket_of(kk[e])], 1);
    __syncthreads();
    for (int k = t; k < NBK; k += 256) hist[c * NBK + k] = h[k];
}

// P2: per batch, exact scatter offset for every (chunk,bucket):
// offs[c][k] = batchBase + (sum of counts of buckets < k) + (count of bucket k
// in chunks before c). One block per batch, thread k owns bucket k.
__global__ __launch_bounds__(1024) void k_offs(const int* __restrict__ hist,
                                               int* __restrict__ offs) {
    __shared__ int sh[NBK];
    int b = blockIdx.x, k = threadIdx.x;
    int part[32]; int run = 0;
    #pragma unroll 32
    for (int cb = 0; cb < 32; cb++) {
        part[cb] = run;
        run += hist[((b << 5) + cb) * NBK + k];
    }
    sh[k] = run;                         // total count of bucket k in batch b
    __syncthreads();
    int v = run;
    for (int off = 1; off < NBK; off <<= 1) {
        int add = (k >= off) ? sh[k - off] : 0;
        __syncthreads();
        sh[k] += add;
        __syncthreads();
    }
    int excl = sh[k] - v + (b << 17);    // bucket k segment start (flat)
    #pragma unroll 32
    for (int cb = 0; cb < 32; cb++)
        offs[((b << 5) + cb) * NBK + k] = excl + part[cb];
}

// P3: scatter (key,li) u64 pairs into exact bucket segments; within-bucket
// rank via LDS atomicAdd (order within bucket irrelevant — dedup takes min).
__global__ void k_scatter(const unsigned int* __restrict__ keys,
                          const int* __restrict__ offs,
                          unsigned long long* __restrict__ pairs) {
    __shared__ int base[NBK];
    __shared__ int cnt[NBK];
    int c = blockIdx.x, t = threadIdx.x;
    for (int k = t; k < NBK; k += 256) { base[k] = offs[c * NBK + k]; cnt[k] = 0; }
    __syncthreads();
    int b = c >> 5, cb = c & 31;
    const unsigned int* kk = keys + (b << 17) + (cb << 12);
    int li0 = cb << 12;
    for (int e = t; e < CHE; e += 256) {
        unsigned int key = kk[e];
        int kb = bucket_of(key);
        int dst = base[kb] + atomicAdd(&cnt[kb], 1);
        pairs[dst] = ((unsigned long long)key << 32) | (unsigned int)(li0 + e);
    }
}

// P4: one block per 8 buckets (~1024 pts). LDS hash: CAS-first claim gives
// exactly one slot per distinct key (slot content never changes after claim;
// a second claim of the same key along the probe chain is impossible);
// LDS atomicMin accumulates min li per voxel. Then per-point lookup (table
// is final after the barrier) -> pfirst scatter.
__global__ void k_dedup(const unsigned long long* __restrict__ pairs,
                        const int* __restrict__ offs,
                        int* __restrict__ pfirst) {
    __shared__ unsigned int ktab[HSLOTS];
    __shared__ int ltab[HSLOTS];
    int g = blockIdx.x, t = threadIdx.x;
    int b = g >> 7;                      // 128 blocks per batch
    int k0 = (g & 127) * BPB;
    for (int s = t; s < HSLOTS; s += 256) { ktab[s] = EMPTY32; ltab[s] = 0x7FFFFFFF; }
    int lo = offs[(b << 5) * NBK + k0];  // chunk 0 offs == bucket segment start
    int hi = (k0 + BPB == NBK) ? ((b + 1) << 17)
                               : offs[(b << 5) * NBK + k0 + BPB];
    __syncthreads();
    for (int idx = lo + t; idx < hi; idx += 256) {
        unsigned long long p = pairs[idx];
        unsigned int key = (unsigned int)(p >> 32);
        int li = (int)(p & 0xFFFFFFFFu);
        unsigned int s = ((key * 0x85EBCA6Bu) >> 20) & HMASK;  // independent hash
        for (;;) {
            unsigned int old = atomicCAS(&ktab[s], EMPTY32, key);
            if (old == EMPTY32 || old == key) { atomicMin(&ltab[s], li); break; }
            s = (s + 1) & HMASK;
        }
    }
    __syncthreads();
    int bbase = b << 17;
    for (int idx = lo + t; idx < hi; idx += 256) {
        unsigned long long p = pairs[idx];
        unsigned int key = (unsigned int)(p >> 32);
        int li = (int)(p & 0xFFFFFFFFu);
        unsigned int s = ((key * 0x85EBCA6Bu) >> 20) & HMASK;
        while (ktab[s] != key) s = (s + 1) & HMASK;   // guaranteed present
        pfirst[bbase + li] = bbase + ltab[s];
    }
}

// Streaming flag pass: first-occurrence bitmask + per-block sums (no gathers).
__global__ void k_scanA2(const int* __restrict__ pfirst,
                         unsigned short* __restrict__ fmask,
                         int* __restrict__ bsums) {
    int blk = blockIdx.x, t = threadIdx.x;
    int base = blk * SCAN_EPB + t * SCAN_EPT;
    const v4i* pv = (const v4i*)(pfirst + base);
    unsigned int bits = 0; int s = 0;
    #pragma unroll
    for (int q = 0; q < 4; q++) {
        v4i p = pv[q];
        #pragma unroll
        for (int e = 0; e < 4; e++) {
            int idx = 4 * q + e;
            int f = (p[e] == base + idx);
            bits |= (unsigned int)f << idx;
            s += f;
        }
    }
    fmask[blk * SCAN_TPB + t] = (unsigned short)bits;
    __shared__ int sh[SCAN_TPB];
    sh[t] = s;
    __syncthreads();
    for (int off = SCAN_TPB / 2; off > 0; off >>= 1) {
        if (t < off) sh[t] += sh[t + off];
        __syncthreads();
    }
    if (t == 0) bsums[blk] = sh[0];
}

// Scan pass C with fused pass B (verified round 2): every block redundantly
// scans the 1024 raw block sums -> block prefix + grand total; then
// per-element exclusive scan; scatter ul_idx_inv[rank] = pos; int4 stores.
__global__ void k_scanC(const unsigned short* __restrict__ fmask,
                        const int* __restrict__ bsums,
                        int* __restrict__ scanArr, float* __restrict__ ulinv,
                        int* __restrict__ scal) {
    int t = threadIdx.x;
    __shared__ int shc[SCAN_TPB];
    int s0 = bsums[4 * t + 0], s1 = bsums[4 * t + 1];
    int s2 = bsums[4 * t + 2], s3 = bsums[4 * t + 3];
    int cs = s0 + s1 + s2 + s3;
    shc[t] = cs;
    __syncthreads();
    for (int off = 1; off < SCAN_TPB; off <<= 1) {
        int add = (t >= off) ? shc[t - off] : 0;
        __syncthreads();
        shc[t] += add;
        __syncthreads();
    }
    __shared__ int bp;
    int q = blockIdx.x >> 2, r = blockIdx.x & 3;
    if (t == q) {
        int ex = shc[t] - cs;
        if (r > 0) ex += s0;
        if (r > 1) ex += s1;
        if (r > 2) ex += s2;
        bp = ex;
    }
    if (blockIdx.x == 0 && t == SCAN_TPB - 1) scal[2] = shc[t];  // total U
    __syncthreads();
    int blockpref = bp;
    unsigned int bits = fmask[blockIdx.x * SCAN_TPB + t];
    int s = __popc(bits);
    __syncthreads();
    shc[t] = s;
    __syncthreads();
    int v = s;
    for (int off = 1; off < SCAN_TPB; off <<= 1) {
        int add = (t >= off) ? shc[t - off] : 0;
        __syncthreads();
        shc[t] += add;
        __syncthreads();
    }
    int prefix = blockpref + shc[t] - v;
    int base = blockIdx.x * SCAN_EPB + t * SCAN_EPT;
    v4i* out = (v4i*)(scanArr + base);
    #pragma unroll
    for (int qq = 0; qq < 4; qq++) {
        v4i o;
        #pragma unroll
        for (int e = 0; e < 4; e++) {
            int idx = 4 * qq + e;
            int f = (bits >> idx) & 1;
            o[e] = prefix;
            if (f) ulinv[prefix] = (float)(base + idx);
            prefix += f;
        }
        out[qq] = o;
    }
}

// Fused (verified round 2): ul_idx gather + ul_idx_inv tail pad + stable
// top-k partition + output gather. y reconstructed exactly from packed key.
__global__ void k_select(const unsigned int* __restrict__ keys,
                         const int* __restrict__ pfirst,
                         const int* __restrict__ scanArr,
                         const unsigned short* __restrict__ fmask,
                         const int* __restrict__ scal,
                         float* __restrict__ ysel, float* __restrict__ idxout,
                         float* __restrict__ msel, float* __restrict__ uli,
                         float* __restrict__ ulinv) {
    int blk = blockIdx.x;                  // BN/1024 = 4096 blocks
    int b = blk & 31;
    int chunk = blk >> 5;                  // 0..127
    int j0 = (chunk << 10) + (threadIdx.x << 2);
    int i0 = (b << 17) + j0;
    v4i pf = *(const v4i*)(pfirst + i0);
    v4i sa = *(const v4i*)(scanArr + i0);
    v4u kv = *(const v4u*)(keys + i0);
    int U = scal[2];
    int base = scanArr[b << 17];
    int cnt1 = ((b == BB - 1) ? U : scanArr[(b + 1) << 17]) - base;
    unsigned int fb = fmask[i0 >> 4];
    v4f ul;
    #pragma unroll
    for (int e = 0; e < 4; e++) ul[e] = (float)scanArr[pf[e]];
    __builtin_nontemporal_store(ul, (v4f*)(uli + i0));
    #pragma unroll
    for (int e = 0; e < 4; e++) {
        int i = i0 + e;
        int j = j0 + e;
        if (i >= U) ulinv[i] = (float)BN;
        int ones_before = sa[e] - base;
        int flag = (fb >> (i & 15)) & 1;
        int pos = flag ? ones_before : cnt1 + (j - ones_before);
        if (pos < TT) {
            unsigned int key = kv[e];
            float y0 = CELL * (float)((int)(key >> 20) - 512);
            float y1 = CELL * (float)((int)((key >> 10) & 1023) - 512);
            float y2 = CELL * (float)((int)(key & 1023) - 512);
            int yo = (b * TT + pos) * 3;
            ysel[yo + 0] = y0;
            ysel[yo + 1] = y1;
            ysel[yo + 2] = y2;
            int io = (b * TT + pos) * 2;
            idxout[io + 0] = (float)b;
            idxout[io + 1] = (float)j;
            msel[b * TT + pos] = flag ? 1.0f : 0.0f;
        }
    }
}

extern "C" void kernel_launch(void* const* d_in, const int* in_sizes, int n_in,
                              void* d_out, int out_size, void* d_ws, size_t ws_size,
                              hipStream_t stream) {
    const float* x = (const float*)d_in[0];
    float* out = (float*)d_out;
    char* ws = (char*)d_ws;

    // ws layout (bytes): scalars 256 | pfirst BN*4 | scanArr BN*4 | bsums 4096
    //  | fmask BN/16*2 | keys BN*4 | hist 4MB | offs 4MB | pairs BN*8  => ~89MB
    int* scal    = (int*)ws;
    int* pfirst  = (int*)(ws + 256);
    int* scanArr = pfirst + BN;
    int* bsums   = scanArr + BN;
    unsigned short* fmask = (unsigned short*)(bsums + 1024);
    unsigned int* keys = (unsigned int*)((char*)fmask + (BN / 16) * 2);
    int* hist = (int*)(keys + BN);
    int* offs = hist + NCH * NBK;
    unsigned long long* pairs = (unsigned long long*)(offs + NCH * NBK);

    k_keygen<<<BN / 4 / 256, 256, 0, stream>>>(x, keys);
    k_hist<<<NCH, 256, 0, stream>>>(keys, hist);
    k_offs<<<BB, 1024, 0, stream>>>(hist, offs);
    k_scatter<<<NCH, 256, 0, stream>>>(keys, offs, pairs);
    k_dedup<<<P4B, 256, 0, stream>>>(pairs, offs, pfirst);
    k_scanA2<<<SCAN_NBLK, SCAN_TPB, 0, stream>>>(pfirst, fmask, bsums);
    k_scanC<<<SCAN_NBLK, SCAN_TPB, 0, stream>>>(fmask, bsums, scanArr, out + ULV_OFF,
                                                scal);
    k_select<<<BN / 1024, 256, 0, stream>>>(keys, pfirst, scanArr, fmask, scal,
                                            out + Y_OFF, out + IDX_OFF, out + MSK_OFF,
                                            out + ULI_OFF, out + ULV_OFF);
}

// Round 6
// 225.410 us; speedup vs baseline: 2.9067x; 1.1657x over previous
//
#include <hip/hip_runtime.h>
#include <stdint.h>

// Problem constants (fixed by reference setup_inputs)
#define BB 32
#define NN 131072            // 2^17 points per batch
#define BN (BB * NN)         // 4,194,304 = 2^22
#define TT 32768             // NUM_POINTS_TARGET
#define CELL 0.05f
#define EMPTY32 0xFFFFFFFFu

// Output layout in d_out (floats), in return order:
// y_sel [32,32768,3], idx_out [32,32768,2], mask_sel [32,32768],
// ul_idx [BN], ul_idx_inv [BN]
#define Y_OFF   0
#define IDX_OFF (BB * TT * 3)                    // 3,145,728
#define MSK_OFF (IDX_OFF + BB * TT * 2)          // 5,242,880
#define ULI_OFF (MSK_OFF + BB * TT)              // 6,291,456
#define ULV_OFF (ULI_OFF + BN)                   // 10,485,760

#define SCAN_TPB 256
#define SCAN_EPT 16
#define SCAN_EPB (SCAN_TPB * SCAN_EPT)           // 4096
#define SCAN_NBLK (BN / SCAN_EPB)                // 1024

// Bucket-partition pipeline (NO global atomics — rounds 0-4 proved every
// global atomic is a memory-side RMW at ~25 G ops/s regardless of scope).
// Round 6: pairs are CHUNK-MAJOR bucket-sorted (each 32 KB chunk window
// written densely by exactly ONE block -> full-line writebacks; round 5's
// batch-major layout had 32 XCD-distributed writers per bucket segment ->
// 3.8x write amplification, 122 MB for 32 MB payload).
#define NBK 1024             // hash buckets per batch
#define CHE 4096             // elems per chunk
#define NCH (BN / CHE)       // 1024 chunks total, 32 per batch
#define BPB 8                // buckets per dedup block
#define P4B (BB * NBK / BPB) // 4096 dedup blocks
#define HSLOTS 4096
#define HMASK (HSLOTS - 1)

typedef float v4f __attribute__((ext_vector_type(4)));
typedef int   v4i __attribute__((ext_vector_type(4)));
typedef unsigned int v4u __attribute__((ext_vector_type(4)));

__device__ __forceinline__ unsigned bucket_of(unsigned key) {
    return (key * 2654435761u) >> 22;            // top 10 bits of mult-hash
}

// Quantize x -> 30-bit packed voxel key. 4 points/thread, float4 loads.
// y is reconstructible exactly: CELL*(float)g == CELL*rintf(x/CELL).
__global__ void k_keygen(const float* __restrict__ x, unsigned int* __restrict__ keys) {
    int t = blockIdx.x * blockDim.x + threadIdx.x;   // handles points 4t..4t+3
    const v4f* xv = (const v4f*)(x + 12 * t);        // 48B per thread, 16B aligned
    v4f va = __builtin_nontemporal_load(xv + 0);
    v4f vb = __builtin_nontemporal_load(xv + 1);
    v4f vc = __builtin_nontemporal_load(xv + 2);
    float p[12];
    p[0] = va[0]; p[1] = va[1]; p[2]  = va[2]; p[3]  = va[3];
    p[4] = vb[0]; p[5] = vb[1]; p[6]  = vb[2]; p[7]  = vb[3];
    p[8] = vc[0]; p[9] = vc[1]; p[10] = vc[2]; p[11] = vc[3];
    v4u kv;
    #pragma unroll
    for (int q = 0; q < 4; q++) {
        int g0 = (int)rintf(p[3 * q + 0] / CELL) + 512;
        int g1 = (int)rintf(p[3 * q + 1] / CELL) + 512;
        int g2 = (int)rintf(p[3 * q + 2] / CELL) + 512;
        g0 = min(max(g0, 0), 1023); g1 = min(max(g1, 0), 1023); g2 = min(max(g2, 0), 1023);
        kv[q] = ((unsigned int)g0 << 20) | ((unsigned int)g1 << 10) | (unsigned int)g2;
    }
    __builtin_nontemporal_store(kv, (v4u*)keys + t);
}

// Fused hist + offsets + scatter: per chunk, keys stay in registers across
// {LDS histogram -> 1024-bucket LDS scan -> LDS atomicAdd rank}; pairs written
// bucket-sorted at pairs[c*CHE + rank] (block-private 32 KB window, L2-merged
// full lines). Per-chunk bucket start offsets (global pair index) -> offs2.
__global__ __launch_bounds__(256) void k_part(const unsigned int* __restrict__ keys,
                                              unsigned long long* __restrict__ pairs,
                                              int* __restrict__ offs2) {
    __shared__ int h[NBK];
    __shared__ int sc[256];
    int c = blockIdx.x, t = threadIdx.x;
    int b = c >> 5, cb = c & 31;
    const unsigned int* kk = keys + (b << 17) + (cb << 12);
    #pragma unroll
    for (int q = 0; q < 4; q++) h[(q << 8) + t] = 0;
    __syncthreads();
    unsigned int key[16];
    #pragma unroll
    for (int q = 0; q < 4; q++) {                // coalesced 16B loads
        v4u kv = *(const v4u*)(kk + (q << 10) + (t << 2));
        key[4 * q + 0] = kv[0]; key[4 * q + 1] = kv[1];
        key[4 * q + 2] = kv[2]; key[4 * q + 3] = kv[3];
    }
    #pragma unroll
    for (int e = 0; e < 16; e++) atomicAdd(&h[bucket_of(key[e])], 1);
    __syncthreads();
    // Exclusive scan over 1024 buckets; thread t owns buckets 4t..4t+3.
    v4i hv = *(v4i*)&h[4 * t];
    int cs = hv[0] + hv[1] + hv[2] + hv[3];
    sc[t] = cs;
    __syncthreads();
    int v = cs;
    for (int off = 1; off < 256; off <<= 1) {
        int add = (t >= off) ? sc[t - off] : 0;
        __syncthreads();
        sc[t] += add;
        __syncthreads();
    }
    int p0 = sc[t] - v;                          // excl prefix of bucket 4t
    int p1 = p0 + hv[0], p2 = p1 + hv[1], p3 = p2 + hv[2];
    int cbase = c << 12;                         // global pair index of chunk start
    v4i ov; ov[0] = cbase + p0; ov[1] = cbase + p1;
    ov[2] = cbase + p2; ov[3] = cbase + p3;
    *(v4i*)(offs2 + c * NBK + 4 * t) = ov;       // coalesced 16B
    h[4 * t + 0] = p0; h[4 * t + 1] = p1;        // running chunk-local offsets
    h[4 * t + 2] = p2; h[4 * t + 3] = p3;
    __syncthreads();
    unsigned long long* pc = pairs + ((size_t)c << 12);
    int li0 = cb << 12;
    #pragma unroll
    for (int q = 0; q < 4; q++) {
        #pragma unroll
        for (int j = 0; j < 4; j++) {
            int e = (q << 10) + (t << 2) + j;    // matches load order
            unsigned int ky = key[4 * q + j];
            int r = atomicAdd(&h[bucket_of(ky)], 1);
            pc[r] = ((unsigned long long)ky << 32) | (unsigned int)(li0 + e);
        }
    }
}

// Dedup: one block per 8 buckets of one batch. Gathers the group's 32
// per-chunk runs (~256B contiguous each, boundaries from offs2), LDS hash:
// CAS-first claim gives exactly one slot per distinct key; LDS atomicMin
// accumulates min li per voxel; then per-point lookup -> pfirst scatter.
// pfirst values identical to round 5 (min over same element set).
__global__ __launch_bounds__(256) void k_dedup(
        const unsigned long long* __restrict__ pairs,
        const int* __restrict__ offs2,
        int* __restrict__ pfirst) {
    __shared__ unsigned int ktab[HSLOTS];
    __shared__ int ltab[HSLOTS];
    __shared__ int rstart[32];
    __shared__ int rpre[33];
    int g = blockIdx.x, t = threadIdx.x;
    int b = g >> 7;                      // 128 blocks per batch
    int k0 = (g & 127) * BPB;
    for (int s = t; s < HSLOTS; s += 256) { ktab[s] = EMPTY32; ltab[s] = 0x7FFFFFFF; }
    if (t < 32) {
        int c = (b << 5) + t;
        int st = offs2[c * NBK + k0];
        int en = (k0 + BPB == NBK) ? ((c + 1) << 12) : offs2[c * NBK + k0 + BPB];
        rstart[t] = st;
        rpre[t] = en - st;               // length, prefixed below
    }
    __syncthreads();
    if (t == 0) {
        int run = 0;
        #pragma unroll
        for (int i = 0; i < 32; i++) { int L = rpre[i]; rpre[i] = run; run += L; }
        rpre[32] = run;
    }
    __syncthreads();
    int total = rpre[32];
    for (int p = t; p < total; p += 256) {
        int lo = 0, hi = 31;             // largest lo with rpre[lo] <= p
        #pragma unroll
        for (int it = 0; it < 5; it++) {
            int mid = (lo + hi + 1) >> 1;
            if (rpre[mid] <= p) lo = mid; else hi = mid - 1;
        }
        unsigned long long pr = pairs[rstart[lo] + (p - rpre[lo])];
        unsigned int ky = (unsigned int)(pr >> 32);
        int li = (int)(pr & 0xFFFFFFFFu);
        unsigned int s = ((ky * 0x85EBCA6Bu) >> 20) & HMASK;
        for (;;) {
            unsigned int old = atomicCAS(&ktab[s], EMPTY32, ky);
            if (old == EMPTY32 || old == ky) { atomicMin(&ltab[s], li); break; }
            s = (s + 1) & HMASK;
        }
    }
    __syncthreads();
    int bbase = b << 17;
    for (int p = t; p < total; p += 256) {
        int lo = 0, hi = 31;
        #pragma unroll
        for (int it = 0; it < 5; it++) {
            int mid = (lo + hi + 1) >> 1;
            if (rpre[mid] <= p) lo = mid; else hi = mid - 1;
        }
        unsigned long long pr = pairs[rstart[lo] + (p - rpre[lo])];
        unsigned int ky = (unsigned int)(pr >> 32);
        int li = (int)(pr & 0xFFFFFFFFu);
        unsigned int s = ((ky * 0x85EBCA6Bu) >> 20) & HMASK;
        while (ktab[s] != ky) s = (s + 1) & HMASK;   // guaranteed present
        pfirst[bbase + li] = bbase + ltab[s];
    }
}

// Streaming flag pass: first-occurrence bitmask + per-block sums (no gathers).
__global__ void k_scanA2(const int* __restrict__ pfirst,
                         unsigned short* __restrict__ fmask,
                         int* __restrict__ bsums) {
    int blk = blockIdx.x, t = threadIdx.x;
    int base = blk * SCAN_EPB + t * SCAN_EPT;
    const v4i* pv = (const v4i*)(pfirst + base);
    unsigned int bits = 0; int s = 0;
    #pragma unroll
    for (int q = 0; q < 4; q++) {
        v4i p = pv[q];
        #pragma unroll
        for (int e = 0; e < 4; e++) {
            int idx = 4 * q + e;
            int f = (p[e] == base + idx);
            bits |= (unsigned int)f << idx;
            s += f;
        }
    }
    fmask[blk * SCAN_TPB + t] = (unsigned short)bits;
    __shared__ int sh[SCAN_TPB];
    sh[t] = s;
    __syncthreads();
    for (int off = SCAN_TPB / 2; off > 0; off >>= 1) {
        if (t < off) sh[t] += sh[t + off];
        __syncthreads();
    }
    if (t == 0) bsums[blk] = sh[0];
}

// Scan pass C with fused pass B (verified round 2): every block redundantly
// scans the 1024 raw block sums -> block prefix + grand total; then
// per-element exclusive scan; scatter ul_idx_inv[rank] = pos; int4 stores.
__global__ void k_scanC(const unsigned short* __restrict__ fmask,
                        const int* __restrict__ bsums,
                        int* __restrict__ scanArr, float* __restrict__ ulinv,
                        int* __restrict__ scal) {
    int t = threadIdx.x;
    __shared__ int shc[SCAN_TPB];
    int s0 = bsums[4 * t + 0], s1 = bsums[4 * t + 1];
    int s2 = bsums[4 * t + 2], s3 = bsums[4 * t + 3];
    int cs = s0 + s1 + s2 + s3;
    shc[t] = cs;
    __syncthreads();
    for (int off = 1; off < SCAN_TPB; off <<= 1) {
        int add = (t >= off) ? shc[t - off] : 0;
        __syncthreads();
        shc[t] += add;
        __syncthreads();
    }
    __shared__ int bp;
    int q = blockIdx.x >> 2, r = blockIdx.x & 3;
    if (t == q) {
        int ex = shc[t] - cs;
        if (r > 0) ex += s0;
        if (r > 1) ex += s1;
        if (r > 2) ex += s2;
        bp = ex;
    }
    if (blockIdx.x == 0 && t == SCAN_TPB - 1) scal[2] = shc[t];  // total U
    __syncthreads();
    int blockpref = bp;
    unsigned int bits = fmask[blockIdx.x * SCAN_TPB + t];
    int s = __popc(bits);
    __syncthreads();
    shc[t] = s;
    __syncthreads();
    int v = s;
    for (int off = 1; off < SCAN_TPB; off <<= 1) {
        int add = (t >= off) ? shc[t - off] : 0;
        __syncthreads();
        shc[t] += add;
        __syncthreads();
    }
    int prefix = blockpref + shc[t] - v;
    int base = blockIdx.x * SCAN_EPB + t * SCAN_EPT;
    v4i* out = (v4i*)(scanArr + base);
    #pragma unroll
    for (int qq = 0; qq < 4; qq++) {
        v4i o;
        #pragma unroll
        for (int e = 0; e < 4; e++) {
            int idx = 4 * qq + e;
            int f = (bits >> idx) & 1;
            o[e] = prefix;
            if (f) ulinv[prefix] = (float)(base + idx);
            prefix += f;
        }
        out[qq] = o;
    }
}

// Fused (verified round 2): ul_idx gather + ul_idx_inv tail pad + stable
// top-k partition + output gather. y reconstructed exactly from packed key.
__global__ void k_select(const unsigned int* __restrict__ keys,
                         const int* __restrict__ pfirst,
                         const int* __restrict__ scanArr,
                         const unsigned short* __restrict__ fmask,
                         const int* __restrict__ scal,
                         float* __restrict__ ysel, float* __restrict__ idxout,
                         float* __restrict__ msel, float* __restrict__ uli,
                         float* __restrict__ ulinv) {
    int blk = blockIdx.x;                  // BN/1024 = 4096 blocks
    int b = blk & 31;
    int chunk = blk >> 5;                  // 0..127
    int j0 = (chunk << 10) + (threadIdx.x << 2);
    int i0 = (b << 17) + j0;
    v4i pf = *(const v4i*)(pfirst + i0);
    v4i sa = *(const v4i*)(scanArr + i0);
    v4u kv = *(const v4u*)(keys + i0);
    int U = scal[2];
    int base = scanArr[b << 17];
    int cnt1 = ((b == BB - 1) ? U : scanArr[(b + 1) << 17]) - base;
    unsigned int fb = fmask[i0 >> 4];
    v4f ul;
    #pragma unroll
    for (int e = 0; e < 4; e++) ul[e] = (float)scanArr[pf[e]];
    __builtin_nontemporal_store(ul, (v4f*)(uli + i0));
    #pragma unroll
    for (int e = 0; e < 4; e++) {
        int i = i0 + e;
        int j = j0 + e;
        if (i >= U) ulinv[i] = (float)BN;
        int ones_before = sa[e] - base;
        int flag = (fb >> (i & 15)) & 1;
        int pos = flag ? ones_before : cnt1 + (j - ones_before);
        if (pos < TT) {
            unsigned int key = kv[e];
            float y0 = CELL * (float)((int)(key >> 20) - 512);
            float y1 = CELL * (float)((int)((key >> 10) & 1023) - 512);
            float y2 = CELL * (float)((int)(key & 1023) - 512);
            int yo = (b * TT + pos) * 3;
            ysel[yo + 0] = y0;
            ysel[yo + 1] = y1;
            ysel[yo + 2] = y2;
            int io = (b * TT + pos) * 2;
            idxout[io + 0] = (float)b;
            idxout[io + 1] = (float)j;
            msel[b * TT + pos] = flag ? 1.0f : 0.0f;
        }
    }
}

extern "C" void kernel_launch(void* const* d_in, const int* in_sizes, int n_in,
                              void* d_out, int out_size, void* d_ws, size_t ws_size,
                              hipStream_t stream) {
    const float* x = (const float*)d_in[0];
    float* out = (float*)d_out;
    char* ws = (char*)d_ws;

    // ws layout (bytes): scalars 256 | pfirst BN*4 | scanArr BN*4 | bsums 4096
    //  | fmask BN/16*2 | keys BN*4 | offs2 4MB | pairs BN*8  => ~85MB
    int* scal    = (int*)ws;
    int* pfirst  = (int*)(ws + 256);
    int* scanArr = pfirst + BN;
    int* bsums   = scanArr + BN;
    unsigned short* fmask = (unsigned short*)(bsums + 1024);
    unsigned int* keys = (unsigned int*)((char*)fmask + (BN / 16) * 2);
    int* offs2 = (int*)(keys + BN);
    unsigned long long* pairs = (unsigned long long*)(offs2 + NCH * NBK);

    k_keygen<<<BN / 4 / 256, 256, 0, stream>>>(x, keys);
    k_part<<<NCH, 256, 0, stream>>>(keys, pairs, offs2);
    k_dedup<<<P4B, 256, 0, stream>>>(pairs, offs2, pfirst);
    k_scanA2<<<SCAN_NBLK, SCAN_TPB, 0, stream>>>(pfirst, fmask, bsums);
    k_scanC<<<SCAN_NBLK, SCAN_TPB, 0, stream>>>(fmask, bsums, scanArr, out + ULV_OFF,
                                                scal);
    k_select<<<BN / 1024, 256, 0, stream>>>(keys, pfirst, scanArr, fmask, scal,
                                            out + Y_OFF, out + IDX_OFF, out + MSK_OFF,
                                            out + ULI_OFF, out + ULV_OFF);
}

// Round 7
// 218.750 us; speedup vs baseline: 2.9952x; 1.0304x over previous
//
#include <hip/hip_runtime.h>
#include <stdint.h>

// Problem constants (fixed by reference setup_inputs)
#define BB 32
#define NN 131072            // 2^17 points per batch
#define BN (BB * NN)         // 4,194,304 = 2^22
#define TT 32768             // NUM_POINTS_TARGET
#define CELL 0.05f
#define EMPTY32 0xFFFFFFFFu
#define EMPTY64 0xFFFFFFFFFFFFFFFFull

// Output layout in d_out (floats), in return order:
// y_sel [32,32768,3], idx_out [32,32768,2], mask_sel [32,32768],
// ul_idx [BN], ul_idx_inv [BN]
#define Y_OFF   0
#define IDX_OFF (BB * TT * 3)                    // 3,145,728
#define MSK_OFF (IDX_OFF + BB * TT * 2)          // 5,242,880
#define ULI_OFF (MSK_OFF + BB * TT)              // 6,291,456
#define ULV_OFF (ULI_OFF + BN)                   // 10,485,760

#define SCAN_TPB 256
#define SCAN_EPT 16
#define SCAN_EPB (SCAN_TPB * SCAN_EPT)           // 4096
#define SCAN_NBLK (BN / SCAN_EPB)                // 1024

// Bucket-partition pipeline (NO global atomics — rounds 0-4 proved every
// global atomic is a memory-side RMW at ~25 G ops/s regardless of scope).
// Pairs are CHUNK-MAJOR bucket-sorted (round 6: single-writer 32 KB windows
// -> full-line writebacks). Round 7: dedup blocks are XCD-batch-affine so the
// 16 writers of each pfirst line share one L2 (round 6 measured 6x write amp
// from cross-XCD partial lines).
#define NBK 1024             // hash buckets per batch
#define CHE 4096             // elems per chunk
#define NCH (BN / CHE)       // 1024 chunks total, 32 per batch
#define BPB 8                // buckets per dedup block
#define P4B (BB * NBK / BPB) // 4096 dedup blocks
#define HSLOTS 4096
#define HMASK (HSLOTS - 1)

typedef float v4f __attribute__((ext_vector_type(4)));
typedef int   v4i __attribute__((ext_vector_type(4)));
typedef unsigned int v4u __attribute__((ext_vector_type(4)));

__device__ __forceinline__ unsigned bucket_of(unsigned key) {
    return (key * 2654435761u) >> 22;            // top 10 bits of mult-hash
}

// Quantize x -> 30-bit packed voxel key. 4 points/thread, float4 loads.
// y is reconstructible exactly: CELL*(float)g == CELL*rintf(x/CELL).
__global__ void k_keygen(const float* __restrict__ x, unsigned int* __restrict__ keys) {
    int t = blockIdx.x * blockDim.x + threadIdx.x;   // handles points 4t..4t+3
    const v4f* xv = (const v4f*)(x + 12 * t);        // 48B per thread, 16B aligned
    v4f va = __builtin_nontemporal_load(xv + 0);
    v4f vb = __builtin_nontemporal_load(xv + 1);
    v4f vc = __builtin_nontemporal_load(xv + 2);
    float p[12];
    p[0] = va[0]; p[1] = va[1]; p[2]  = va[2]; p[3]  = va[3];
    p[4] = vb[0]; p[5] = vb[1]; p[6]  = vb[2]; p[7]  = vb[3];
    p[8] = vc[0]; p[9] = vc[1]; p[10] = vc[2]; p[11] = vc[3];
    v4u kv;
    #pragma unroll
    for (int q = 0; q < 4; q++) {
        int g0 = (int)rintf(p[3 * q + 0] / CELL) + 512;
        int g1 = (int)rintf(p[3 * q + 1] / CELL) + 512;
        int g2 = (int)rintf(p[3 * q + 2] / CELL) + 512;
        g0 = min(max(g0, 0), 1023); g1 = min(max(g1, 0), 1023); g2 = min(max(g2, 0), 1023);
        kv[q] = ((unsigned int)g0 << 20) | ((unsigned int)g1 << 10) | (unsigned int)g2;
    }
    __builtin_nontemporal_store(kv, (v4u*)keys + t);
}

// Fused hist + offsets + scatter: per chunk, keys stay in registers across
// {LDS histogram -> 1024-bucket LDS scan -> LDS atomicAdd rank}; pairs written
// bucket-sorted at pairs[c*CHE + rank] (block-private 32 KB window, L2-merged
// full lines). Per-chunk bucket start offsets (global pair index) -> offs2.
__global__ __launch_bounds__(256) void k_part(const unsigned int* __restrict__ keys,
                                              unsigned long long* __restrict__ pairs,
                                              int* __restrict__ offs2) {
    __shared__ int h[NBK];
    __shared__ int sc[256];
    int c = blockIdx.x, t = threadIdx.x;
    int b = c >> 5, cb = c & 31;
    const unsigned int* kk = keys + (b << 17) + (cb << 12);
    #pragma unroll
    for (int q = 0; q < 4; q++) h[(q << 8) + t] = 0;
    __syncthreads();
    unsigned int key[16];
    #pragma unroll
    for (int q = 0; q < 4; q++) {                // coalesced 16B loads
        v4u kv = *(const v4u*)(kk + (q << 10) + (t << 2));
        key[4 * q + 0] = kv[0]; key[4 * q + 1] = kv[1];
        key[4 * q + 2] = kv[2]; key[4 * q + 3] = kv[3];
    }
    #pragma unroll
    for (int e = 0; e < 16; e++) atomicAdd(&h[bucket_of(key[e])], 1);
    __syncthreads();
    // Exclusive scan over 1024 buckets; thread t owns buckets 4t..4t+3.
    v4i hv = *(v4i*)&h[4 * t];
    int cs = hv[0] + hv[1] + hv[2] + hv[3];
    sc[t] = cs;
    __syncthreads();
    int v = cs;
    for (int off = 1; off < 256; off <<= 1) {
        int add = (t >= off) ? sc[t - off] : 0;
        __syncthreads();
        sc[t] += add;
        __syncthreads();
    }
    int p0 = sc[t] - v;                          // excl prefix of bucket 4t
    int p1 = p0 + hv[0], p2 = p1 + hv[1], p3 = p2 + hv[2];
    int cbase = c << 12;                         // global pair index of chunk start
    v4i ov; ov[0] = cbase + p0; ov[1] = cbase + p1;
    ov[2] = cbase + p2; ov[3] = cbase + p3;
    *(v4i*)(offs2 + c * NBK + 4 * t) = ov;       // coalesced 16B
    h[4 * t + 0] = p0; h[4 * t + 1] = p1;        // running chunk-local offsets
    h[4 * t + 2] = p2; h[4 * t + 3] = p3;
    __syncthreads();
    unsigned long long* pc = pairs + ((size_t)c << 12);
    int li0 = cb << 12;
    #pragma unroll
    for (int q = 0; q < 4; q++) {
        #pragma unroll
        for (int j = 0; j < 4; j++) {
            int e = (q << 10) + (t << 2) + j;    // matches load order
            unsigned int ky = key[4 * q + j];
            int r = atomicAdd(&h[bucket_of(ky)], 1);
            pc[r] = ((unsigned long long)ky << 32) | (unsigned int)(li0 + e);
        }
    }
}

// Dedup: one block per 8 buckets of one batch. ROUND 7 block mapping:
// blk = slot*1024 + inner*8 + xcd, batch b = slot*8+xcd, k0 = inner*8 =>
// under round-robin dispatch each batch's 128 blocks run CONSECUTIVELY on ONE
// XCD, so all writers of each pfirst 64B line (16 consecutive points -> ~16
// different bucket-blocks) share one L2 and partial lines merge before
// writeback (round 6: cross-XCD writers -> 97 MB written for 16 MB payload).
// Single u64 LDS table, entry=(key<<17)|li: CAS-claim carries li, same-key
// losers do one 64-bit atomicMin (min over same-key packs = min li); pass 2
// is one LDS read per point. pfirst values identical to round 6.
__global__ __launch_bounds__(256) void k_dedup(
        const unsigned long long* __restrict__ pairs,
        const int* __restrict__ offs2,
        int* __restrict__ pfirst) {
    __shared__ unsigned long long ptab[HSLOTS];
    __shared__ int rstart[32];
    __shared__ int rpre[33];
    int g = blockIdx.x, t = threadIdx.x;
    int xcd = g & 7;
    int inner = (g >> 3) & 127;
    int slot = g >> 10;                  // 0..3
    int b = (slot << 3) | xcd;           // batch; all its blocks on XCD b%8
    int k0 = inner * BPB;
    for (int s = t; s < HSLOTS; s += 256) ptab[s] = EMPTY64;
    if (t < 32) {
        int c = (b << 5) + t;
        int st = offs2[c * NBK + k0];
        int en = (k0 + BPB == NBK) ? ((c + 1) << 12) : offs2[c * NBK + k0 + BPB];
        rstart[t] = st;
        rpre[t] = en - st;               // length, prefixed below
    }
    __syncthreads();
    if (t == 0) {
        int run = 0;
        #pragma unroll
        for (int i = 0; i < 32; i++) { int L = rpre[i]; rpre[i] = run; run += L; }
        rpre[32] = run;
    }
    __syncthreads();
    int total = rpre[32];
    for (int p = t; p < total; p += 256) {
        int lo = 0, hi = 31;             // largest lo with rpre[lo] <= p
        #pragma unroll
        for (int it = 0; it < 5; it++) {
            int mid = (lo + hi + 1) >> 1;
            if (rpre[mid] <= p) lo = mid; else hi = mid - 1;
        }
        unsigned long long pr = pairs[rstart[lo] + (p - rpre[lo])];
        unsigned int ky = (unsigned int)(pr >> 32);
        unsigned int li = (unsigned int)(pr & 0xFFFFFFFFu);
        unsigned long long mine = ((unsigned long long)ky << 17) | li;
        unsigned int s = ((ky * 0x85EBCA6Bu) >> 20) & HMASK;
        for (;;) {
            unsigned long long old = atomicCAS(&ptab[s], EMPTY64, mine);
            if (old == EMPTY64) break;                    // claimed (li included)
            if ((unsigned int)(old >> 17) == ky) {        // same voxel
                if (mine < old) atomicMin(&ptab[s], mine);
                break;
            }
            s = (s + 1) & HMASK;
        }
    }
    __syncthreads();
    int bbase = b << 17;
    for (int p = t; p < total; p += 256) {
        int lo = 0, hi = 31;
        #pragma unroll
        for (int it = 0; it < 5; it++) {
            int mid = (lo + hi + 1) >> 1;
            if (rpre[mid] <= p) lo = mid; else hi = mid - 1;
        }
        unsigned long long pr = pairs[rstart[lo] + (p - rpre[lo])];
        unsigned int ky = (unsigned int)(pr >> 32);
        unsigned int li = (unsigned int)(pr & 0xFFFFFFFFu);
        unsigned int s = ((ky * 0x85EBCA6Bu) >> 20) & HMASK;
        unsigned long long e;
        while ((unsigned int)((e = ptab[s]) >> 17) != ky) s = (s + 1) & HMASK;
        pfirst[bbase + li] = bbase + (int)(e & 0x1FFFFu);
    }
}

// Streaming flag pass: first-occurrence bitmask + per-block sums (no gathers).
__global__ void k_scanA2(const int* __restrict__ pfirst,
                         unsigned short* __restrict__ fmask,
                         int* __restrict__ bsums) {
    int blk = blockIdx.x, t = threadIdx.x;
    int base = blk * SCAN_EPB + t * SCAN_EPT;
    const v4i* pv = (const v4i*)(pfirst + base);
    unsigned int bits = 0; int s = 0;
    #pragma unroll
    for (int q = 0; q < 4; q++) {
        v4i p = pv[q];
        #pragma unroll
        for (int e = 0; e < 4; e++) {
            int idx = 4 * q + e;
            int f = (p[e] == base + idx);
            bits |= (unsigned int)f << idx;
            s += f;
        }
    }
    fmask[blk * SCAN_TPB + t] = (unsigned short)bits;
    __shared__ int sh[SCAN_TPB];
    sh[t] = s;
    __syncthreads();
    for (int off = SCAN_TPB / 2; off > 0; off >>= 1) {
        if (t < off) sh[t] += sh[t + off];
        __syncthreads();
    }
    if (t == 0) bsums[blk] = sh[0];
}

// Scan pass C with fused pass B (verified round 2): every block redundantly
// scans the 1024 raw block sums -> block prefix + grand total; then
// per-element exclusive scan; scatter ul_idx_inv[rank] = pos; int4 stores.
__global__ void k_scanC(const unsigned short* __restrict__ fmask,
                        const int* __restrict__ bsums,
                        int* __restrict__ scanArr, float* __restrict__ ulinv,
                        int* __restrict__ scal) {
    int t = threadIdx.x;
    __shared__ int shc[SCAN_TPB];
    int s0 = bsums[4 * t + 0], s1 = bsums[4 * t + 1];
    int s2 = bsums[4 * t + 2], s3 = bsums[4 * t + 3];
    int cs = s0 + s1 + s2 + s3;
    shc[t] = cs;
    __syncthreads();
    for (int off = 1; off < SCAN_TPB; off <<= 1) {
        int add = (t >= off) ? shc[t - off] : 0;
        __syncthreads();
        shc[t] += add;
        __syncthreads();
    }
    __shared__ int bp;
    int q = blockIdx.x >> 2, r = blockIdx.x & 3;
    if (t == q) {
        int ex = shc[t] - cs;
        if (r > 0) ex += s0;
        if (r > 1) ex += s1;
        if (r > 2) ex += s2;
        bp = ex;
    }
    if (blockIdx.x == 0 && t == SCAN_TPB - 1) scal[2] = shc[t];  // total U
    __syncthreads();
    int blockpref = bp;
    unsigned int bits = fmask[blockIdx.x * SCAN_TPB + t];
    int s = __popc(bits);
    __syncthreads();
    shc[t] = s;
    __syncthreads();
    int v = s;
    for (int off = 1; off < SCAN_TPB; off <<= 1) {
        int add = (t >= off) ? shc[t - off] : 0;
        __syncthreads();
        shc[t] += add;
        __syncthreads();
    }
    int prefix = blockpref + shc[t] - v;
    int base = blockIdx.x * SCAN_EPB + t * SCAN_EPT;
    v4i* out = (v4i*)(scanArr + base);
    #pragma unroll
    for (int qq = 0; qq < 4; qq++) {
        v4i o;
        #pragma unroll
        for (int e = 0; e < 4; e++) {
            int idx = 4 * qq + e;
            int f = (bits >> idx) & 1;
            o[e] = prefix;
            if (f) ulinv[prefix] = (float)(base + idx);
            prefix += f;
        }
        out[qq] = o;
    }
}

// Fused (verified round 2): ul_idx gather + ul_idx_inv tail pad + stable
// top-k partition + output gather. y reconstructed exactly from packed key.
__global__ void k_select(const unsigned int* __restrict__ keys,
                         const int* __restrict__ pfirst,
                         const int* __restrict__ scanArr,
                         const unsigned short* __restrict__ fmask,
                         const int* __restrict__ scal,
                         float* __restrict__ ysel, float* __restrict__ idxout,
                         float* __restrict__ msel, float* __restrict__ uli,
                         float* __restrict__ ulinv) {
    int blk = blockIdx.x;                  // BN/1024 = 4096 blocks
    int b = blk & 31;
    int chunk = blk >> 5;                  // 0..127
    int j0 = (chunk << 10) + (threadIdx.x << 2);
    int i0 = (b << 17) + j0;
    v4i pf = *(const v4i*)(pfirst + i0);
    v4i sa = *(const v4i*)(scanArr + i0);
    v4u kv = *(const v4u*)(keys + i0);
    int U = scal[2];
    int base = scanArr[b << 17];
    int cnt1 = ((b == BB - 1) ? U : scanArr[(b + 1) << 17]) - base;
    unsigned int fb = fmask[i0 >> 4];
    v4f ul;
    #pragma unroll
    for (int e = 0; e < 4; e++) ul[e] = (float)scanArr[pf[e]];
    __builtin_nontemporal_store(ul, (v4f*)(uli + i0));
    #pragma unroll
    for (int e = 0; e < 4; e++) {
        int i = i0 + e;
        int j = j0 + e;
        if (i >= U) ulinv[i] = (float)BN;
        int ones_before = sa[e] - base;
        int flag = (fb >> (i & 15)) & 1;
        int pos = flag ? ones_before : cnt1 + (j - ones_before);
        if (pos < TT) {
            unsigned int key = kv[e];
            float y0 = CELL * (float)((int)(key >> 20) - 512);
            float y1 = CELL * (float)((int)((key >> 10) & 1023) - 512);
            float y2 = CELL * (float)((int)(key & 1023) - 512);
            int yo = (b * TT + pos) * 3;
            ysel[yo + 0] = y0;
            ysel[yo + 1] = y1;
            ysel[yo + 2] = y2;
            int io = (b * TT + pos) * 2;
            idxout[io + 0] = (float)b;
            idxout[io + 1] = (float)j;
            msel[b * TT + pos] = flag ? 1.0f : 0.0f;
        }
    }
}

extern "C" void kernel_launch(void* const* d_in, const int* in_sizes, int n_in,
                              void* d_out, int out_size, void* d_ws, size_t ws_size,
                              hipStream_t stream) {
    const float* x = (const float*)d_in[0];
    float* out = (float*)d_out;
    char* ws = (char*)d_ws;

    // ws layout (bytes): scalars 256 | pfirst BN*4 | scanArr BN*4 | bsums 4096
    //  | fmask BN/16*2 | keys BN*4 | offs2 4MB | pairs BN*8  => ~85MB
    int* scal    = (int*)ws;
    int* pfirst  = (int*)(ws + 256);
    int* scanArr = pfirst + BN;
    int* bsums   = scanArr + BN;
    unsigned short* fmask = (unsigned short*)(bsums + 1024);
    unsigned int* keys = (unsigned int*)((char*)fmask + (BN / 16) * 2);
    int* offs2 = (int*)(keys + BN);
    unsigned long long* pairs = (unsigned long long*)(offs2 + NCH * NBK);

    k_keygen<<<BN / 4 / 256, 256, 0, stream>>>(x, keys);
    k_part<<<NCH, 256, 0, stream>>>(keys, pairs, offs2);
    k_dedup<<<P4B, 256, 0, stream>>>(pairs, offs2, pfirst);
    k_scanA2<<<SCAN_NBLK, SCAN_TPB, 0, stream>>>(pfirst, fmask, bsums);
    k_scanC<<<SCAN_NBLK, SCAN_TPB, 0, stream>>>(fmask, bsums, scanArr, out + ULV_OFF,
                                                scal);
    k_select<<<BN / 1024, 256, 0, stream>>>(keys, pfirst, scanArr, fmask, scal,
                                            out + Y_OFF, out + IDX_OFF, out + MSK_OFF,
                                            out + ULI_OFF, out + ULV_OFF);
}

// Round 8
// 211.402 us; speedup vs baseline: 3.0993x; 1.0348x over previous
//
#include <hip/hip_runtime.h>
#include <stdint.h>

// Problem constants (fixed by reference setup_inputs)
#define BB 32
#define NN 131072            // 2^17 points per batch
#define BN (BB * NN)         // 4,194,304 = 2^22
#define TT 32768             // NUM_POINTS_TARGET
#define CELL 0.05f
#define EMPTY32 0xFFFFFFFFu
#define EMPTY64 0xFFFFFFFFFFFFFFFFull
#define LI17 0x1FFFFu

// Output layout in d_out (floats), in return order:
// y_sel [32,32768,3], idx_out [32,32768,2], mask_sel [32,32768],
// ul_idx [BN], ul_idx_inv [BN]
#define Y_OFF   0
#define IDX_OFF (BB * TT * 3)                    // 3,145,728
#define MSK_OFF (IDX_OFF + BB * TT * 2)          // 5,242,880
#define ULI_OFF (MSK_OFF + BB * TT)              // 6,291,456
#define ULV_OFF (ULI_OFF + BN)                   // 10,485,760

#define SCAN_TPB 256
#define SCAN_EPT 16
#define SCAN_EPB (SCAN_TPB * SCAN_EPT)           // 4096
#define SCAN_NBLK (BN / SCAN_EPB)                // 1024

// Bucket-partition pipeline (NO global atomics — rounds 0-4 proved every
// global atomic is a memory-side RMW at ~25 G ops/s regardless of scope).
// Pairs are CHUNK-MAJOR bucket-sorted (round 6: single-writer 32 KB windows
// -> full-line writebacks). Dedup blocks are XCD-batch-affine (round 7:
// pfirst write amp 6x -> 1x, WRITE == payload). Round 8: dedup is
// latency-bound (HBM 10%, occ 34%) -> HSLOTS 2048 (16.7 KB LDS, 8 blk/CU),
// slot-register pass 2 (no pairs re-read / binary search / re-probe),
// pairs pre-packed (key<<17)|li.
#define NBK 1024             // hash buckets per batch
#define CHE 4096             // elems per chunk
#define NCH (BN / CHE)       // 1024 chunks total, 32 per batch
#define BPB 8                // buckets per dedup block
#define P4B (BB * NBK / BPB) // 4096 dedup blocks
#define HSLOTS 2048
#define HMASK (HSLOTS - 1)

typedef float v4f __attribute__((ext_vector_type(4)));
typedef int   v4i __attribute__((ext_vector_type(4)));
typedef unsigned int v4u __attribute__((ext_vector_type(4)));

__device__ __forceinline__ unsigned bucket_of(unsigned key) {
    return (key * 2654435761u) >> 22;            // top 10 bits of mult-hash
}

// Quantize x -> 30-bit packed voxel key. 4 points/thread, float4 loads.
// y is reconstructible exactly: CELL*(float)g == CELL*rintf(x/CELL).
__global__ void k_keygen(const float* __restrict__ x, unsigned int* __restrict__ keys) {
    int t = blockIdx.x * blockDim.x + threadIdx.x;   // handles points 4t..4t+3
    const v4f* xv = (const v4f*)(x + 12 * t);        // 48B per thread, 16B aligned
    v4f va = __builtin_nontemporal_load(xv + 0);
    v4f vb = __builtin_nontemporal_load(xv + 1);
    v4f vc = __builtin_nontemporal_load(xv + 2);
    float p[12];
    p[0] = va[0]; p[1] = va[1]; p[2]  = va[2]; p[3]  = va[3];
    p[4] = vb[0]; p[5] = vb[1]; p[6]  = vb[2]; p[7]  = vb[3];
    p[8] = vc[0]; p[9] = vc[1]; p[10] = vc[2]; p[11] = vc[3];
    v4u kv;
    #pragma unroll
    for (int q = 0; q < 4; q++) {
        int g0 = (int)rintf(p[3 * q + 0] / CELL) + 512;
        int g1 = (int)rintf(p[3 * q + 1] / CELL) + 512;
        int g2 = (int)rintf(p[3 * q + 2] / CELL) + 512;
        g0 = min(max(g0, 0), 1023); g1 = min(max(g1, 0), 1023); g2 = min(max(g2, 0), 1023);
        kv[q] = ((unsigned int)g0 << 20) | ((unsigned int)g1 << 10) | (unsigned int)g2;
    }
    __builtin_nontemporal_store(kv, (v4u*)keys + t);
}

// Fused hist + offsets + scatter: per chunk, keys stay in registers across
// {LDS histogram -> 1024-bucket LDS scan -> LDS atomicAdd rank}; pairs written
// bucket-sorted at pairs[c*CHE + rank] (block-private 32 KB window, L2-merged
// full lines), packed as (key<<17)|li so dedup uses them as CAS payload
// directly. Per-chunk bucket start offsets (global pair index) -> offs2.
__global__ __launch_bounds__(256) void k_part(const unsigned int* __restrict__ keys,
                                              unsigned long long* __restrict__ pairs,
                                              int* __restrict__ offs2) {
    __shared__ int h[NBK];
    __shared__ int sc[256];
    int c = blockIdx.x, t = threadIdx.x;
    int b = c >> 5, cb = c & 31;
    const unsigned int* kk = keys + (b << 17) + (cb << 12);
    #pragma unroll
    for (int q = 0; q < 4; q++) h[(q << 8) + t] = 0;
    __syncthreads();
    unsigned int key[16];
    #pragma unroll
    for (int q = 0; q < 4; q++) {                // coalesced 16B loads
        v4u kv = *(const v4u*)(kk + (q << 10) + (t << 2));
        key[4 * q + 0] = kv[0]; key[4 * q + 1] = kv[1];
        key[4 * q + 2] = kv[2]; key[4 * q + 3] = kv[3];
    }
    #pragma unroll
    for (int e = 0; e < 16; e++) atomicAdd(&h[bucket_of(key[e])], 1);
    __syncthreads();
    // Exclusive scan over 1024 buckets; thread t owns buckets 4t..4t+3.
    v4i hv = *(v4i*)&h[4 * t];
    int cs = hv[0] + hv[1] + hv[2] + hv[3];
    sc[t] = cs;
    __syncthreads();
    int v = cs;
    for (int off = 1; off < 256; off <<= 1) {
        int add = (t >= off) ? sc[t - off] : 0;
        __syncthreads();
        sc[t] += add;
        __syncthreads();
    }
    int p0 = sc[t] - v;                          // excl prefix of bucket 4t
    int p1 = p0 + hv[0], p2 = p1 + hv[1], p3 = p2 + hv[2];
    int cbase = c << 12;                         // global pair index of chunk start
    v4i ov; ov[0] = cbase + p0; ov[1] = cbase + p1;
    ov[2] = cbase + p2; ov[3] = cbase + p3;
    *(v4i*)(offs2 + c * NBK + 4 * t) = ov;       // coalesced 16B
    h[4 * t + 0] = p0; h[4 * t + 1] = p1;        // running chunk-local offsets
    h[4 * t + 2] = p2; h[4 * t + 3] = p3;
    __syncthreads();
    unsigned long long* pc = pairs + ((size_t)c << 12);
    int li0 = cb << 12;
    #pragma unroll
    for (int q = 0; q < 4; q++) {
        #pragma unroll
        for (int j = 0; j < 4; j++) {
            int e = (q << 10) + (t << 2) + j;    // matches load order
            unsigned int ky = key[4 * q + j];
            int r = atomicAdd(&h[bucket_of(ky)], 1);
            pc[r] = ((unsigned long long)ky << 17) | (unsigned int)(li0 + e);
        }
    }
}

// Dedup: one block per 8 buckets of one batch, XCD-batch-affine mapping
// (blk = slot*1024 + inner*8 + xcd => all of batch b's blocks on XCD b%8;
// pfirst lines merge in one L2 before writeback). u64 LDS table,
// entry == pair == (key<<17)|li: CAS-claim carries li; same-key losers do one
// 64-bit atomicMin (min over same-key packs = min li). Pass 1 records each
// point's resolved slot in REGISTERS (statically-indexed marr[8]; total is
// ~1024 +/- 43, so 2048 covers with huge margin; strided overflow loop keeps
// the old re-probe path for correctness). Pass 2: one LDS read + store per
// point — no pairs re-read, no binary search, no re-probe.
__global__ __launch_bounds__(256) void k_dedup(
        const unsigned long long* __restrict__ pairs,
        const int* __restrict__ offs2,
        int* __restrict__ pfirst) {
    __shared__ unsigned long long ptab[HSLOTS];
    __shared__ int rstart[32];
    __shared__ int rpre[33];
    int g = blockIdx.x, t = threadIdx.x;
    int xcd = g & 7;
    int inner = (g >> 3) & 127;
    int slot = g >> 10;                  // 0..3
    int b = (slot << 3) | xcd;           // batch; all its blocks on XCD b%8
    int k0 = inner * BPB;
    #pragma unroll
    for (int q = 0; q < HSLOTS / 256; q++) ptab[(q << 8) + t] = EMPTY64;
    if (t < 32) {
        int c = (b << 5) + t;
        int st = offs2[c * NBK + k0];
        int en = (k0 + BPB == NBK) ? ((c + 1) << 12) : offs2[c * NBK + k0 + BPB];
        rstart[t] = st;
        rpre[t] = en - st;               // length, prefixed below
    }
    __syncthreads();
    if (t == 0) {
        int run = 0;
        #pragma unroll
        for (int i = 0; i < 32; i++) { int L = rpre[i]; rpre[i] = run; run += L; }
        rpre[32] = run;
    }
    __syncthreads();
    int total = rpre[32];
    unsigned int marr[8];                // statically indexed (rule #20)
    #pragma unroll 8
    for (int k = 0; k < 8; k++) {
        int p = t + (k << 8);
        if (p < total) {
            int lo = 0, hi = 31;         // largest lo with rpre[lo] <= p
            #pragma unroll
            for (int it = 0; it < 5; it++) {
                int mid = (lo + hi + 1) >> 1;
                if (rpre[mid] <= p) lo = mid; else hi = mid - 1;
            }
            unsigned long long pr = pairs[rstart[lo] + (p - rpre[lo])];
            unsigned int ky = (unsigned int)(pr >> 17);
            unsigned int li = (unsigned int)pr & LI17;
            unsigned int s = ((ky * 0x85EBCA6Bu) >> 20) & HMASK;
            for (;;) {
                unsigned long long old = atomicCAS(&ptab[s], EMPTY64, pr);
                if (old == EMPTY64) break;                // claimed (li included)
                if ((unsigned int)(old >> 17) == ky) {    // same voxel
                    if (pr < old) atomicMin(&ptab[s], pr);
                    break;
                }
                s = (s + 1) & HMASK;
            }
            marr[k] = (s << 17) | li;
        }
    }
    for (int p = t + 2048; p < total; p += 256) {   // overflow (ultra-rare)
        int lo = 0, hi = 31;
        #pragma unroll
        for (int it = 0; it < 5; it++) {
            int mid = (lo + hi + 1) >> 1;
            if (rpre[mid] <= p) lo = mid; else hi = mid - 1;
        }
        unsigned long long pr = pairs[rstart[lo] + (p - rpre[lo])];
        unsigned int ky = (unsigned int)(pr >> 17);
        unsigned int s = ((ky * 0x85EBCA6Bu) >> 20) & HMASK;
        for (;;) {
            unsigned long long old = atomicCAS(&ptab[s], EMPTY64, pr);
            if (old == EMPTY64) break;
            if ((unsigned int)(old >> 17) == ky) {
                if (pr < old) atomicMin(&ptab[s], pr);
                break;
            }
            s = (s + 1) & HMASK;
        }
    }
    __syncthreads();
    int bbase = b << 17;
    #pragma unroll 8
    for (int k = 0; k < 8; k++) {
        int p = t + (k << 8);
        if (p < total) {
            unsigned int m = marr[k];
            unsigned long long e = ptab[m >> 17];
            pfirst[bbase + (m & LI17)] = bbase + (int)(e & LI17);
        }
    }
    for (int p = t + 2048; p < total; p += 256) {   // overflow writes
        int lo = 0, hi = 31;
        #pragma unroll
        for (int it = 0; it < 5; it++) {
            int mid = (lo + hi + 1) >> 1;
            if (rpre[mid] <= p) lo = mid; else hi = mid - 1;
        }
        unsigned long long pr = pairs[rstart[lo] + (p - rpre[lo])];
        unsigned int ky = (unsigned int)(pr >> 17);
        unsigned int li = (unsigned int)pr & LI17;
        unsigned int s = ((ky * 0x85EBCA6Bu) >> 20) & HMASK;
        unsigned long long e;
        while ((unsigned int)((e = ptab[s]) >> 17) != ky) s = (s + 1) & HMASK;
        pfirst[bbase + li] = bbase + (int)(e & LI17);
    }
}

// Streaming flag pass: first-occurrence bitmask + per-block sums (no gathers).
__global__ void k_scanA2(const int* __restrict__ pfirst,
                         unsigned short* __restrict__ fmask,
                         int* __restrict__ bsums) {
    int blk = blockIdx.x, t = threadIdx.x;
    int base = blk * SCAN_EPB + t * SCAN_EPT;
    const v4i* pv = (const v4i*)(pfirst + base);
    unsigned int bits = 0; int s = 0;
    #pragma unroll
    for (int q = 0; q < 4; q++) {
        v4i p = pv[q];
        #pragma unroll
        for (int e = 0; e < 4; e++) {
            int idx = 4 * q + e;
            int f = (p[e] == base + idx);
            bits |= (unsigned int)f << idx;
            s += f;
        }
    }
    fmask[blk * SCAN_TPB + t] = (unsigned short)bits;
    __shared__ int sh[SCAN_TPB];
    sh[t] = s;
    __syncthreads();
    for (int off = SCAN_TPB / 2; off > 0; off >>= 1) {
        if (t < off) sh[t] += sh[t + off];
        __syncthreads();
    }
    if (t == 0) bsums[blk] = sh[0];
}

// Scan pass C with fused pass B (verified round 2): every block redundantly
// scans the 1024 raw block sums -> block prefix + grand total; then
// per-element exclusive scan; scatter ul_idx_inv[rank] = pos; int4 stores.
__global__ void k_scanC(const unsigned short* __restrict__ fmask,
                        const int* __restrict__ bsums,
                        int* __restrict__ scanArr, float* __restrict__ ulinv,
                        int* __restrict__ scal) {
    int t = threadIdx.x;
    __shared__ int shc[SCAN_TPB];
    int s0 = bsums[4 * t + 0], s1 = bsums[4 * t + 1];
    int s2 = bsums[4 * t + 2], s3 = bsums[4 * t + 3];
    int cs = s0 + s1 + s2 + s3;
    shc[t] = cs;
    __syncthreads();
    for (int off = 1; off < SCAN_TPB; off <<= 1) {
        int add = (t >= off) ? shc[t - off] : 0;
        __syncthreads();
        shc[t] += add;
        __syncthreads();
    }
    __shared__ int bp;
    int q = blockIdx.x >> 2, r = blockIdx.x & 3;
    if (t == q) {
        int ex = shc[t] - cs;
        if (r > 0) ex += s0;
        if (r > 1) ex += s1;
        if (r > 2) ex += s2;
        bp = ex;
    }
    if (blockIdx.x == 0 && t == SCAN_TPB - 1) scal[2] = shc[t];  // total U
    __syncthreads();
    int blockpref = bp;
    unsigned int bits = fmask[blockIdx.x * SCAN_TPB + t];
    int s = __popc(bits);
    __syncthreads();
    shc[t] = s;
    __syncthreads();
    int v = s;
    for (int off = 1; off < SCAN_TPB; off <<= 1) {
        int add = (t >= off) ? shc[t - off] : 0;
        __syncthreads();
        shc[t] += add;
        __syncthreads();
    }
    int prefix = blockpref + shc[t] - v;
    int base = blockIdx.x * SCAN_EPB + t * SCAN_EPT;
    v4i* out = (v4i*)(scanArr + base);
    #pragma unroll
    for (int qq = 0; qq < 4; qq++) {
        v4i o;
        #pragma unroll
        for (int e = 0; e < 4; e++) {
            int idx = 4 * qq + e;
            int f = (bits >> idx) & 1;
            o[e] = prefix;
            if (f) ulinv[prefix] = (float)(base + idx);
            prefix += f;
        }
        out[qq] = o;
    }
}

// Fused (verified round 2): ul_idx gather + ul_idx_inv tail pad + stable
// top-k partition + output gather. y reconstructed exactly from packed key.
__global__ void k_select(const unsigned int* __restrict__ keys,
                         const int* __restrict__ pfirst,
                         const int* __restrict__ scanArr,
                         const unsigned short* __restrict__ fmask,
                         const int* __restrict__ scal,
                         float* __restrict__ ysel, float* __restrict__ idxout,
                         float* __restrict__ msel, float* __restrict__ uli,
                         float* __restrict__ ulinv) {
    int blk = blockIdx.x;                  // BN/1024 = 4096 blocks
    int b = blk & 31;
    int chunk = blk >> 5;                  // 0..127
    int j0 = (chunk << 10) + (threadIdx.x << 2);
    int i0 = (b << 17) + j0;
    v4i pf = *(const v4i*)(pfirst + i0);
    v4i sa = *(const v4i*)(scanArr + i0);
    v4u kv = *(const v4u*)(keys + i0);
    int U = scal[2];
    int base = scanArr[b << 17];
    int cnt1 = ((b == BB - 1) ? U : scanArr[(b + 1) << 17]) - base;
    unsigned int fb = fmask[i0 >> 4];
    v4f ul;
    #pragma unroll
    for (int e = 0; e < 4; e++) ul[e] = (float)scanArr[pf[e]];
    __builtin_nontemporal_store(ul, (v4f*)(uli + i0));
    #pragma unroll
    for (int e = 0; e < 4; e++) {
        int i = i0 + e;
        int j = j0 + e;
        if (i >= U) ulinv[i] = (float)BN;
        int ones_before = sa[e] - base;
        int flag = (fb >> (i & 15)) & 1;
        int pos = flag ? ones_before : cnt1 + (j - ones_before);
        if (pos < TT) {
            unsigned int key = kv[e];
            float y0 = CELL * (float)((int)(key >> 20) - 512);
            float y1 = CELL * (float)((int)((key >> 10) & 1023) - 512);
            float y2 = CELL * (float)((int)(key & 1023) - 512);
            int yo = (b * TT + pos) * 3;
            ysel[yo + 0] = y0;
            ysel[yo + 1] = y1;
            ysel[yo + 2] = y2;
            int io = (b * TT + pos) * 2;
            idxout[io + 0] = (float)b;
            idxout[io + 1] = (float)j;
            msel[b * TT + pos] = flag ? 1.0f : 0.0f;
        }
    }
}

extern "C" void kernel_launch(void* const* d_in, const int* in_sizes, int n_in,
                              void* d_out, int out_size, void* d_ws, size_t ws_size,
                              hipStream_t stream) {
    const float* x = (const float*)d_in[0];
    float* out = (float*)d_out;
    char* ws = (char*)d_ws;

    // ws layout (bytes): scalars 256 | pfirst BN*4 | scanArr BN*4 | bsums 4096
    //  | fmask BN/16*2 | keys BN*4 | offs2 4MB | pairs BN*8  => ~85MB
    int* scal    = (int*)ws;
    int* pfirst  = (int*)(ws + 256);
    int* scanArr = pfirst + BN;
    int* bsums   = scanArr + BN;
    unsigned short* fmask = (unsigned short*)(bsums + 1024);
    unsigned int* keys = (unsigned int*)((char*)fmask + (BN / 16) * 2);
    int* offs2 = (int*)(keys + BN);
    unsigned long long* pairs = (unsigned long long*)(offs2 + NCH * NBK);

    k_keygen<<<BN / 4 / 256, 256, 0, stream>>>(x, keys);
    k_part<<<NCH, 256, 0, stream>>>(keys, pairs, offs2);
    k_dedup<<<P4B, 256, 0, stream>>>(pairs, offs2, pfirst);
    k_scanA2<<<SCAN_NBLK, SCAN_TPB, 0, stream>>>(pfirst, fmask, bsums);
    k_scanC<<<SCAN_NBLK, SCAN_TPB, 0, stream>>>(fmask, bsums, scanArr, out + ULV_OFF,
                                                scal);
    k_select<<<BN / 1024, 256, 0, stream>>>(keys, pfirst, scanArr, fmask, scal,
                                            out + Y_OFF, out + IDX_OFF, out + MSK_OFF,
                                            out + ULI_OFF, out + ULV_OFF);
}